// Round 1
// baseline (454.277 us; speedup 1.0000x reference)
//
#include <hip/hip_runtime.h>
#include <math.h>

// Problem constants
// B=64, CLN=32, QL=32, IH=16, IW=16, IDF=8192, CDF=256, SL=128
// input : [64][32][32][16][16] fp32   (b, cln, ql, ih, iw)
// context:[64][256][128] fp32
// W     : [8192][256] fp32
// out0  : wc [64][32][32][16][16] fp32 (16777216)
// out1  : attnT [64][128][32] fp32     (262144)

#define ZK 16                      // split-K for GEMM1
#define KCH 512                    // 8192 / ZK
#define TWPART_ELEMS (ZK * 2048 * 256)   // 8388608 floats (32 MB)

// ---------------------------------------------------------------------------
// K1: tW_partial[z][m][c] = sum_{d in chunk z} targetT[m][d] * W[d][c]
//     m = b*32+q ; targetT[m][d] = input[b*262144 + (d>>8)*8192 + q*256 + (d&255)]
//     tile 64(m) x 64(c), BK=32, 64 threads, 8x8 micro-tile
// ---------------------------------------------------------------------------
__global__ __launch_bounds__(64) void k1_gemm_tw(const float* __restrict__ inp,
                                                 const float* __restrict__ Wm,
                                                 float* __restrict__ tWpart) {
    const int c0 = blockIdx.x * 64;
    const int m0 = blockIdx.y * 64;
    const int kz = blockIdx.z;
    const int t  = threadIdx.x;
    __shared__ float AsT[32][68];   // [kk][row]
    __shared__ float Ws [32][68];   // [kk][col]
    const int rg = t >> 3;          // 0..7 -> rows rg*8..+7
    const int cg = t & 7;           // cols cg*8..+7
    float acc[8][8];
#pragma unroll
    for (int i = 0; i < 8; ++i)
#pragma unroll
        for (int j = 0; j < 8; ++j) acc[i][j] = 0.f;

    for (int it = 0; it < KCH / 32; ++it) {
        const int k0 = kz * KCH + it * 32;
        const long a_ch = (long)(k0 >> 8) * 8192 + (k0 & 255);
        // stage A: 64 rows x 32 k (transposed into AsT[kk][row])
#pragma unroll
        for (int i = 0; i < 8; ++i) {
            int v = i * 64 + t;        // 0..511 float4 id
            int row = v >> 3;          // 0..63
            int kb = (v & 7) * 4;      // 0..28
            int m = m0 + row;
            int bb = m >> 5, q = m & 31;
            const float4 av = *(const float4*)(inp + (long)bb * 262144 + a_ch + q * 256 + kb);
            AsT[kb + 0][row] = av.x;
            AsT[kb + 1][row] = av.y;
            AsT[kb + 2][row] = av.z;
            AsT[kb + 3][row] = av.w;
        }
        // stage W: 32 k x 64 c (natural layout)
#pragma unroll
        for (int i = 0; i < 8; ++i) {
            int v = i * 64 + t;        // 0..511
            int kk = v >> 4;           // 0..31
            int cb = (v & 15) * 4;     // 0..60
            *(float4*)&Ws[kk][cb] = *(const float4*)(Wm + (long)(k0 + kk) * 256 + c0 + cb);
        }
        __syncthreads();
#pragma unroll 8
        for (int kk = 0; kk < 32; ++kk) {
            float4 a0 = *(const float4*)&AsT[kk][rg * 8];
            float4 a1 = *(const float4*)&AsT[kk][rg * 8 + 4];
            float4 w0 = *(const float4*)&Ws[kk][cg * 8];
            float4 w1 = *(const float4*)&Ws[kk][cg * 8 + 4];
            float aa[8] = {a0.x, a0.y, a0.z, a0.w, a1.x, a1.y, a1.z, a1.w};
            float ww[8] = {w0.x, w0.y, w0.z, w0.w, w1.x, w1.y, w1.z, w1.w};
#pragma unroll
            for (int i = 0; i < 8; ++i)
#pragma unroll
                for (int j = 0; j < 8; ++j)
                    acc[i][j] = fmaf(aa[i], ww[j], acc[i][j]);
        }
        __syncthreads();
    }
    float* outp = tWpart + (long)kz * (2048 * 256);
#pragma unroll
    for (int i = 0; i < 8; ++i) {
        int m = m0 + rg * 8 + i;
        *(float4*)(outp + (long)m * 256 + c0 + cg * 8) =
            make_float4(acc[i][0], acc[i][1], acc[i][2], acc[i][3]);
        *(float4*)(outp + (long)m * 256 + c0 + cg * 8 + 4) =
            make_float4(acc[i][4], acc[i][5], acc[i][6], acc[i][7]);
    }
}

// ---------------------------------------------------------------------------
// K2: reduce split-K partials -> tW rows; logits = tW @ context[b];
//     softmax over s (128); write attnT[b][s][q] (output 1).
//     One block per (b, q-pair); 64 threads; each 32-lane half owns one q row
//     holding all 128 s as float4.
// ---------------------------------------------------------------------------
__global__ __launch_bounds__(64) void k2_logits_softmax(const float* __restrict__ tWpart,
                                                        const float* __restrict__ ctx,
                                                        float* __restrict__ attnT) {
    const int qp = blockIdx.x;      // q0 = qp*2
    const int b  = blockIdx.y;
    const int t  = threadIdx.x;
    __shared__ float tw2[2][256];
#pragma unroll
    for (int i = 0; i < 8; ++i) {
        int e = i * 64 + t;         // 0..511
        int qq = e >> 8;
        int c  = e & 255;
        float s = 0.f;
#pragma unroll
        for (int z = 0; z < ZK; ++z)
            s += tWpart[(long)z * (2048 * 256) + (long)(b * 32 + qp * 2 + qq) * 256 + c];
        tw2[qq][c] = s;
    }
    __syncthreads();
    const int h = t >> 5;           // which q of the pair
    const int l = t & 31;           // s4 = l*4
    const float* ctxb = ctx + (long)b * (256 * 128);
    float4 acc = make_float4(0.f, 0.f, 0.f, 0.f);
    for (int c = 0; c < 256; ++c) {
        float tw = tw2[h][c];
        float4 cv = *(const float4*)(ctxb + c * 128 + l * 4);
        acc.x = fmaf(tw, cv.x, acc.x);
        acc.y = fmaf(tw, cv.y, acc.y);
        acc.z = fmaf(tw, cv.z, acc.z);
        acc.w = fmaf(tw, cv.w, acc.w);
    }
    // softmax across the 32-lane half (each lane holds 4 s-values)
    float mx = fmaxf(fmaxf(acc.x, acc.y), fmaxf(acc.z, acc.w));
#pragma unroll
    for (int m = 1; m <= 16; m <<= 1) mx = fmaxf(mx, __shfl_xor(mx, m));
    float4 ev;
    ev.x = expf(acc.x - mx);
    ev.y = expf(acc.y - mx);
    ev.z = expf(acc.z - mx);
    ev.w = expf(acc.w - mx);
    float sm = ev.x + ev.y + ev.z + ev.w;
#pragma unroll
    for (int m = 1; m <= 16; m <<= 1) sm += __shfl_xor(sm, m);
    float inv = 1.f / sm;
    ev.x *= inv; ev.y *= inv; ev.z *= inv; ev.w *= inv;
    float* o = attnT + (long)b * (128 * 32) + qp * 2 + h;
    o[(l * 4 + 0) * 32] = ev.x;
    o[(l * 4 + 1) * 32] = ev.y;
    o[(l * 4 + 2) * 32] = ev.z;
    o[(l * 4 + 3) * 32] = ev.w;
}

// ---------------------------------------------------------------------------
// K3: ctxA[b][c][q] = sum_s ctx[b][c][s] * attnT[b][s][q]
//     block = (c-chunk of 32, b); 256 threads; thread owns (c, 4 q's)
// ---------------------------------------------------------------------------
__global__ __launch_bounds__(256) void k3_ctxA(const float* __restrict__ ctx,
                                               const float* __restrict__ attnT,
                                               float* __restrict__ ctxA) {
    const int c0 = blockIdx.x * 32;
    const int b  = blockIdx.y;
    const int t  = threadIdx.x;
    __shared__ float at[128][36];   // attnT[s][q]
    __shared__ float cs[32][132];   // ctx chunk [c][s]
#pragma unroll
    for (int i = 0; i < 4; ++i) {
        int v = i * 256 + t;        // f4 id 0..1023
        int e = v * 4;
        int s = e >> 5;
        int qb = e & 31;
        *(float4*)&at[s][qb] = *(const float4*)(attnT + (long)b * 4096 + e);
    }
#pragma unroll
    for (int i = 0; i < 4; ++i) {
        int v = i * 256 + t;
        int c = v >> 5;             // 0..31
        int sb = (v & 31) * 4;      // 0..124
        *(float4*)&cs[c][sb] = *(const float4*)(ctx + (long)b * 32768 + (long)(c0 + c) * 128 + sb);
    }
    __syncthreads();
    const int c  = t >> 3;          // 0..31
    const int qb = (t & 7) * 4;     // 0..28
    float4 acc = make_float4(0.f, 0.f, 0.f, 0.f);
    for (int s = 0; s < 128; ++s) {
        float a = cs[c][s];
        float4 p = *(const float4*)&at[s][qb];
        acc.x = fmaf(a, p.x, acc.x);
        acc.y = fmaf(a, p.y, acc.y);
        acc.z = fmaf(a, p.z, acc.z);
        acc.w = fmaf(a, p.w, acc.w);
    }
    *(float4*)(ctxA + (long)b * 8192 + (long)(c0 + c) * 32 + qb) = acc;
}

// ---------------------------------------------------------------------------
// K4: wc[b] = W[8192x256] @ ctxA[b][256x32], scatter-write with the
//     .view-faithful layout:
//     out0[b*262144 + ((d>>3)&31)*8192 + (d>>8)*256 + (d&7)*32 + q]
//     tile 128(d) x 32(q), BK=32, 64 threads, 8x8 micro-tile
// ---------------------------------------------------------------------------
__global__ __launch_bounds__(64) void k4_wc(const float* __restrict__ Wm,
                                            const float* __restrict__ ctxA,
                                            float* __restrict__ out0) {
    const int m0 = blockIdx.x * 128;
    const int b  = blockIdx.y;
    const int t  = threadIdx.x;
    __shared__ float WsT[32][132];  // [kk][dd]
    __shared__ float cA [32][36];   // [kk][q]
    const int rg = t >> 2;          // 0..15 -> rows rg*8..+7
    const int cg = t & 3;           // q cg*8..+7
    float acc[8][8];
#pragma unroll
    for (int i = 0; i < 8; ++i)
#pragma unroll
        for (int j = 0; j < 8; ++j) acc[i][j] = 0.f;

    for (int ch = 0; ch < 8; ++ch) {
        const int k0 = ch * 32;
        // stage W tile transposed: 128 dd x 32 kk
#pragma unroll
        for (int i = 0; i < 16; ++i) {
            int v = i * 64 + t;     // f4 id 0..1023
            int dd = v >> 3;        // 0..127
            int kb = (v & 7) * 4;   // 0..28
            float4 wv = *(const float4*)(Wm + (long)(m0 + dd) * 256 + k0 + kb);
            WsT[kb + 0][dd] = wv.x;
            WsT[kb + 1][dd] = wv.y;
            WsT[kb + 2][dd] = wv.z;
            WsT[kb + 3][dd] = wv.w;
        }
        // stage ctxA chunk: 32 kk x 32 q
#pragma unroll
        for (int i = 0; i < 4; ++i) {
            int v = i * 64 + t;     // 0..255
            int kk = v >> 3;        // 0..31
            int qb = (v & 7) * 4;   // 0..28
            *(float4*)&cA[kk][qb] = *(const float4*)(ctxA + (long)b * 8192 + (long)(k0 + kk) * 32 + qb);
        }
        __syncthreads();
#pragma unroll 8
        for (int kk = 0; kk < 32; ++kk) {
            float4 a0 = *(const float4*)&WsT[kk][rg * 8];
            float4 a1 = *(const float4*)&WsT[kk][rg * 8 + 4];
            float4 b0 = *(const float4*)&cA[kk][cg * 8];
            float4 b1 = *(const float4*)&cA[kk][cg * 8 + 4];
            float aa[8] = {a0.x, a0.y, a0.z, a0.w, a1.x, a1.y, a1.z, a1.w};
            float bb[8] = {b0.x, b0.y, b0.z, b0.w, b1.x, b1.y, b1.z, b1.w};
#pragma unroll
            for (int i = 0; i < 8; ++i)
#pragma unroll
                for (int j = 0; j < 8; ++j)
                    acc[i][j] = fmaf(aa[i], bb[j], acc[i][j]);
        }
        __syncthreads();
    }
    // epilogue: faithful .view scatter; per (d) the 32 q's are contiguous
#pragma unroll
    for (int i = 0; i < 8; ++i) {
        int d = m0 + rg * 8 + i;
        long base = (long)b * 262144 + (long)((d >> 3) & 31) * 8192 +
                    (long)(d >> 8) * 256 + (d & 7) * 32 + cg * 8;
        *(float4*)(out0 + base) = make_float4(acc[i][0], acc[i][1], acc[i][2], acc[i][3]);
        *(float4*)(out0 + base + 4) = make_float4(acc[i][4], acc[i][5], acc[i][6], acc[i][7]);
    }
}

// ---------------------------------------------------------------------------
extern "C" void kernel_launch(void* const* d_in, const int* in_sizes, int n_in,
                              void* d_out, int out_size, void* d_ws, size_t ws_size,
                              hipStream_t stream) {
    const float* inp = (const float*)d_in[0];   // 16777216
    const float* ctx = (const float*)d_in[1];   // 2097152
    const float* Wm  = (const float*)d_in[2];   // 2097152
    float* out0 = (float*)d_out;                // wc: 16777216
    float* out1 = out0 + 16777216;              // attnT: 262144
    float* wsf = (float*)d_ws;
    float* tWpart = wsf;                        // 8388608 floats
    float* ctxA   = wsf + TWPART_ELEMS;         // 524288 floats

    hipLaunchKernelGGL(k1_gemm_tw, dim3(4, 32, ZK), dim3(64), 0, stream, inp, Wm, tWpart);
    hipLaunchKernelGGL(k2_logits_softmax, dim3(16, 64), dim3(64), 0, stream, tWpart, ctx, out1);
    hipLaunchKernelGGL(k3_ctxA, dim3(8, 64), dim3(256), 0, stream, ctx, out1, ctxA);
    hipLaunchKernelGGL(k4_wc, dim3(64, 64), dim3(64), 0, stream, Wm, ctxA, out0);
}

// Round 2
// 264.014 us; speedup vs baseline: 1.7207x; 1.7207x over previous
//
#include <hip/hip_runtime.h>
#include <math.h>

// B=64, CLN=32, QL=32, IH=16, IW=16, IDF=8192, CDF=256, SL=128
// input : [64][32][32][16][16] fp32 ; context:[64][256][128] fp32 ; W:[8192][256] fp32
// out0: wc fp32 (16777216) ; out1: attnT [64][128][32] fp32 (262144)
//
// Pipeline:
//  k0: W -> Wt_hi/Wt_lo [256][8192] bf16 (transposed, for k1 B) + Wb_hi [8192][256] bf16 (k4 A)
//  k1: tWpart[z][m][c] = targetT @ W  (MFMA bf16 hi/lo 3-pass, split-K=8)
//  k2: reduce partials, logits = tW @ ctx, softmax -> attnT (out1, fp32)
//  k3: ctxAq[b*32+q][c] = sum_s ctx[b][c][s]*attnT[b][s][q]  (fp32 acc -> bf16, transposed)
//  k4: wc = W @ ctxA per batch (MFMA bf16), .view-faithful scatter epilogue

#define ZK 8

typedef short bf16x8 __attribute__((ext_vector_type(8)));
typedef float f32x4 __attribute__((ext_vector_type(4)));
typedef unsigned short us8 __attribute__((ext_vector_type(8)));
typedef unsigned short us4 __attribute__((ext_vector_type(4)));

__device__ __forceinline__ unsigned short f2bf(float f) {
    unsigned int u = __float_as_uint(f);
    return (unsigned short)((u + 0x7fffu + ((u >> 16) & 1u)) >> 16);
}
__device__ __forceinline__ float bf2f(unsigned short s) {
    return __uint_as_float(((unsigned int)s) << 16);
}

// ---------------------------------------------------------------------------
// K0: prep W. grid (128, 4) x 256 thr. 64d x 64c tile.
// ---------------------------------------------------------------------------
__global__ __launch_bounds__(256) void k0_prep(const float* __restrict__ Wm,
                                               unsigned short* __restrict__ Wt_hi,
                                               unsigned short* __restrict__ Wt_lo,
                                               unsigned short* __restrict__ Wb_hi) {
    const int d0 = blockIdx.x * 64;
    const int c0 = blockIdx.y * 64;
    const int t = threadIdx.x;
    __shared__ float tile[64][68];
    {
        const int r = t >> 2, seg = (t & 3) * 16;
        const float* src = Wm + (long)(d0 + r) * 256 + c0 + seg;
        unsigned short* dst = Wb_hi + (long)(d0 + r) * 256 + c0 + seg;
#pragma unroll
        for (int i = 0; i < 4; ++i) {
            float4 v = *(const float4*)(src + i * 4);
            tile[r][seg + i * 4 + 0] = v.x;
            tile[r][seg + i * 4 + 1] = v.y;
            tile[r][seg + i * 4 + 2] = v.z;
            tile[r][seg + i * 4 + 3] = v.w;
            us4 hv;
            hv[0] = f2bf(v.x); hv[1] = f2bf(v.y); hv[2] = f2bf(v.z); hv[3] = f2bf(v.w);
            *(us4*)(dst + i * 4) = hv;
        }
    }
    __syncthreads();
    {
        const int cc = t >> 2, seg = (t & 3) * 16;
        us8 hv0, hv1, lv0, lv1;
#pragma unroll
        for (int j = 0; j < 8; ++j) {
            float f = tile[seg + j][cc];
            unsigned short hs = f2bf(f);
            hv0[j] = hs; lv0[j] = f2bf(f - bf2f(hs));
        }
#pragma unroll
        for (int j = 0; j < 8; ++j) {
            float f = tile[seg + 8 + j][cc];
            unsigned short hs = f2bf(f);
            hv1[j] = hs; lv1[j] = f2bf(f - bf2f(hs));
        }
        long o = (long)(c0 + cc) * 8192 + d0 + seg;
        *(us8*)(Wt_hi + o) = hv0;  *(us8*)(Wt_hi + o + 8) = hv1;
        *(us8*)(Wt_lo + o) = lv0;  *(us8*)(Wt_lo + o + 8) = lv1;
    }
}

// ---------------------------------------------------------------------------
// K1: tWpart = targetT @ W, MFMA bf16 hi/lo. grid (2 n, 16 m, 8 kz) x 256.
// Frag-order LDS: slot(msub, lane) = (msub*64+lane)*8 ushorts, lane=(m&15)+16*(k>>3)
// ---------------------------------------------------------------------------
__global__ __launch_bounds__(256) void k1_mfma(const float* __restrict__ inp,
                                               const unsigned short* __restrict__ Wt_hi,
                                               const unsigned short* __restrict__ Wt_lo,
                                               float* __restrict__ tWpart) {
    const int n0 = blockIdx.x * 128;
    const int m0 = blockIdx.y * 128;
    const int kz = blockIdx.z;
    const int t = threadIdx.x;
    const int lane = t & 63, wv = t >> 6;
    __shared__ unsigned short Ah[4096], Al[4096], Bh[4096], Bl[4096];
    const int r = t >> 1, h = t & 1;
    const int slot0 = ((r >> 4) * 64 + (r & 15) + 16 * (h * 2 + 0)) * 8;
    const int slot1 = slot0 + 128;                       // next k-group (+16 lanes)*8
    const int m = m0 + r;
    const float* arowb = inp + (long)(m >> 5) * 262144 + (long)(m & 31) * 256 + h * 16;
    const unsigned short* wth = Wt_hi + (long)(n0 + r) * 8192 + kz * 1024 + h * 16;
    const unsigned short* wtl = Wt_lo + (long)(n0 + r) * 8192 + kz * 1024 + h * 16;
    const int mh = (wv >> 1) * 4, nh = (wv & 1) * 4;

    f32x4 zero = {0.f, 0.f, 0.f, 0.f};
    f32x4 acc[4][4];
#pragma unroll
    for (int i = 0; i < 4; ++i)
#pragma unroll
        for (int j = 0; j < 4; ++j) acc[i][j] = zero;

    for (int it = 0; it < 32; ++it) {
        const int k0 = kz * 1024 + it * 32;
        const float* ap = arowb + (k0 >> 8) * 8192 + (k0 & 255);
        float4 f0 = *(const float4*)(ap);
        float4 f1 = *(const float4*)(ap + 4);
        float4 f2 = *(const float4*)(ap + 8);
        float4 f3 = *(const float4*)(ap + 12);
        uint4 bh0 = *(const uint4*)(wth + it * 32);
        uint4 bh1 = *(const uint4*)(wth + it * 32 + 8);
        uint4 bl0 = *(const uint4*)(wtl + it * 32);
        uint4 bl1 = *(const uint4*)(wtl + it * 32 + 8);
        float ff[16] = {f0.x, f0.y, f0.z, f0.w, f1.x, f1.y, f1.z, f1.w,
                        f2.x, f2.y, f2.z, f2.w, f3.x, f3.y, f3.z, f3.w};
        us8 ahv0, ahv1, alv0, alv1;
#pragma unroll
        for (int j = 0; j < 8; ++j) {
            unsigned short hs = f2bf(ff[j]);
            ahv0[j] = hs; alv0[j] = f2bf(ff[j] - bf2f(hs));
        }
#pragma unroll
        for (int j = 0; j < 8; ++j) {
            unsigned short hs = f2bf(ff[8 + j]);
            ahv1[j] = hs; alv1[j] = f2bf(ff[8 + j] - bf2f(hs));
        }
        __syncthreads();   // all waves done reading previous tile
        *(us8*)&Ah[slot0] = ahv0;  *(us8*)&Ah[slot1] = ahv1;
        *(us8*)&Al[slot0] = alv0;  *(us8*)&Al[slot1] = alv1;
        *(uint4*)&Bh[slot0] = bh0; *(uint4*)&Bh[slot1] = bh1;
        *(uint4*)&Bl[slot0] = bl0; *(uint4*)&Bl[slot1] = bl1;
        __syncthreads();
        bf16x8 fah[4], fal[4], fbh[4], fbl[4];
#pragma unroll
        for (int i = 0; i < 4; ++i) {
            fah[i] = *(const bf16x8*)&Ah[((mh + i) * 64 + lane) * 8];
            fal[i] = *(const bf16x8*)&Al[((mh + i) * 64 + lane) * 8];
            fbh[i] = *(const bf16x8*)&Bh[((nh + i) * 64 + lane) * 8];
            fbl[i] = *(const bf16x8*)&Bl[((nh + i) * 64 + lane) * 8];
        }
#pragma unroll
        for (int i = 0; i < 4; ++i)
#pragma unroll
            for (int j = 0; j < 4; ++j) {
                acc[i][j] = __builtin_amdgcn_mfma_f32_16x16x32_bf16(fah[i], fbh[j], acc[i][j], 0, 0, 0);
                acc[i][j] = __builtin_amdgcn_mfma_f32_16x16x32_bf16(fah[i], fbl[j], acc[i][j], 0, 0, 0);
                acc[i][j] = __builtin_amdgcn_mfma_f32_16x16x32_bf16(fal[i], fbh[j], acc[i][j], 0, 0, 0);
            }
    }
    float* outp = tWpart + (long)kz * 524288;
    const int col = lane & 15, rq = (lane >> 4) * 4;
#pragma unroll
    for (int i = 0; i < 4; ++i) {
        const int mrow = m0 + (wv >> 1) * 64 + i * 16 + rq;
#pragma unroll
        for (int j = 0; j < 4; ++j) {
            const int cc = n0 + (wv & 1) * 64 + j * 16 + col;
#pragma unroll
            for (int rg = 0; rg < 4; ++rg)
                outp[(long)(mrow + rg) * 256 + cc] = acc[i][j][rg];
        }
    }
}

// ---------------------------------------------------------------------------
// K2: reduce split-K partials; logits = tW @ ctx[b]; softmax; write attnT.
// ---------------------------------------------------------------------------
__global__ __launch_bounds__(64) void k2_logits_softmax(const float* __restrict__ tWpart,
                                                        const float* __restrict__ ctx,
                                                        float* __restrict__ attnT) {
    const int qp = blockIdx.x;
    const int b  = blockIdx.y;
    const int t  = threadIdx.x;
    __shared__ float tw2[2][256];
#pragma unroll
    for (int i = 0; i < 8; ++i) {
        int e = i * 64 + t;
        int qq = e >> 8;
        int c  = e & 255;
        float s = 0.f;
#pragma unroll
        for (int z = 0; z < ZK; ++z)
            s += tWpart[(long)z * 524288 + (long)(b * 32 + qp * 2 + qq) * 256 + c];
        tw2[qq][c] = s;
    }
    __syncthreads();
    const int h = t >> 5;
    const int l = t & 31;
    const float* ctxb = ctx + (long)b * 32768;
    float4 acc = make_float4(0.f, 0.f, 0.f, 0.f);
    for (int c = 0; c < 256; ++c) {
        float tw = tw2[h][c];
        float4 cv = *(const float4*)(ctxb + c * 128 + l * 4);
        acc.x = fmaf(tw, cv.x, acc.x);
        acc.y = fmaf(tw, cv.y, acc.y);
        acc.z = fmaf(tw, cv.z, acc.z);
        acc.w = fmaf(tw, cv.w, acc.w);
    }
    float mx = fmaxf(fmaxf(acc.x, acc.y), fmaxf(acc.z, acc.w));
#pragma unroll
    for (int m = 1; m <= 16; m <<= 1) mx = fmaxf(mx, __shfl_xor(mx, m));
    float4 ev;
    ev.x = expf(acc.x - mx);
    ev.y = expf(acc.y - mx);
    ev.z = expf(acc.z - mx);
    ev.w = expf(acc.w - mx);
    float sm = ev.x + ev.y + ev.z + ev.w;
#pragma unroll
    for (int m = 1; m <= 16; m <<= 1) sm += __shfl_xor(sm, m);
    float inv = 1.f / sm;
    ev.x *= inv; ev.y *= inv; ev.z *= inv; ev.w *= inv;
    float* o = attnT + (long)b * 4096 + qp * 2 + h;
    o[(l * 4 + 0) * 32] = ev.x;
    o[(l * 4 + 1) * 32] = ev.y;
    o[(l * 4 + 2) * 32] = ev.z;
    o[(l * 4 + 3) * 32] = ev.w;
}

// ---------------------------------------------------------------------------
// K3: ctxAq[b*32+q][c] = sum_s ctx[b][c][s] * attnT[b][s][q]  -> bf16
// grid (64) x 256 thr
// ---------------------------------------------------------------------------
__global__ __launch_bounds__(256) void k3_ctxA(const float* __restrict__ ctx,
                                               const float* __restrict__ attnT,
                                               unsigned short* __restrict__ ctxAq) {
    const int b = blockIdx.x;
    const int t = threadIdx.x;
    __shared__ float at[4096];      // [s][q]
    __shared__ float cs[32][132];
#pragma unroll
    for (int i = 0; i < 4; ++i)
        *(float4*)&at[i * 1024 + t * 4] = *(const float4*)(attnT + (long)b * 4096 + i * 1024 + t * 4);
    const int q = t & 31, ci = t >> 5;   // ci 0..7 -> 4 c's each per chunk
    for (int ch = 0; ch < 8; ++ch) {
        __syncthreads();
#pragma unroll
        for (int i = 0; i < 4; ++i) {
            int idx = i * 256 + t;
            int c = idx >> 5, sseg = (idx & 31) * 4;
            *(float4*)&cs[c][sseg] = *(const float4*)(ctx + (long)b * 32768 + (long)(ch * 32 + c) * 128 + sseg);
        }
        __syncthreads();
        float acc0 = 0.f, acc1 = 0.f, acc2 = 0.f, acc3 = 0.f;
#pragma unroll 4
        for (int s4 = 0; s4 < 128; s4 += 4) {
            float w0 = at[(s4 + 0) * 32 + q];
            float w1 = at[(s4 + 1) * 32 + q];
            float w2 = at[(s4 + 2) * 32 + q];
            float w3 = at[(s4 + 3) * 32 + q];
            float4 c0v = *(const float4*)&cs[ci * 4 + 0][s4];
            float4 c1v = *(const float4*)&cs[ci * 4 + 1][s4];
            float4 c2v = *(const float4*)&cs[ci * 4 + 2][s4];
            float4 c3v = *(const float4*)&cs[ci * 4 + 3][s4];
            acc0 += c0v.x * w0 + c0v.y * w1 + c0v.z * w2 + c0v.w * w3;
            acc1 += c1v.x * w0 + c1v.y * w1 + c1v.z * w2 + c1v.w * w3;
            acc2 += c2v.x * w0 + c2v.y * w1 + c2v.z * w2 + c2v.w * w3;
            acc3 += c3v.x * w0 + c3v.y * w1 + c3v.z * w2 + c3v.w * w3;
        }
        us4 o;
        o[0] = f2bf(acc0); o[1] = f2bf(acc1); o[2] = f2bf(acc2); o[3] = f2bf(acc3);
        *(us4*)(ctxAq + (long)(b * 32 + q) * 256 + ch * 32 + ci * 4) = o;
    }
}

// ---------------------------------------------------------------------------
// K4: wc = W @ ctxA (per batch), MFMA bf16, n = 4 batches x 32 q.
// grid (64 m-tiles, 16 b-groups) x 256 thr.
// ---------------------------------------------------------------------------
__global__ __launch_bounds__(256) void k4_mfma(const unsigned short* __restrict__ Wb_hi,
                                               const unsigned short* __restrict__ ctxAq,
                                               float* __restrict__ out0) {
    const int m0 = blockIdx.x * 128;
    const int b0 = blockIdx.y * 4;
    const int t = threadIdx.x;
    const int lane = t & 63, wv = t >> 6;
    __shared__ unsigned short Ah[4096], Bh[4096];
    const int r = t >> 1, h = t & 1;
    const int slot0 = ((r >> 4) * 64 + (r & 15) + 16 * (h * 2 + 0)) * 8;
    const int slot1 = slot0 + 128;
    const unsigned short* wbp = Wb_hi + (long)(m0 + r) * 256 + h * 16;
    const unsigned short* cap = ctxAq + (long)(b0 * 32 + r) * 256 + h * 16;
    const int mh = (wv >> 1) * 4, nh = (wv & 1) * 4;

    f32x4 zero = {0.f, 0.f, 0.f, 0.f};
    f32x4 acc[4][4];
#pragma unroll
    for (int i = 0; i < 4; ++i)
#pragma unroll
        for (int j = 0; j < 4; ++j) acc[i][j] = zero;

    for (int it = 0; it < 8; ++it) {
        uint4 a0 = *(const uint4*)(wbp + it * 32);
        uint4 a1 = *(const uint4*)(wbp + it * 32 + 8);
        uint4 b0v = *(const uint4*)(cap + it * 32);
        uint4 b1v = *(const uint4*)(cap + it * 32 + 8);
        __syncthreads();
        *(uint4*)&Ah[slot0] = a0;  *(uint4*)&Ah[slot1] = a1;
        *(uint4*)&Bh[slot0] = b0v; *(uint4*)&Bh[slot1] = b1v;
        __syncthreads();
        bf16x8 fa[4], fb[4];
#pragma unroll
        for (int i = 0; i < 4; ++i) {
            fa[i] = *(const bf16x8*)&Ah[((mh + i) * 64 + lane) * 8];
            fb[i] = *(const bf16x8*)&Bh[((nh + i) * 64 + lane) * 8];
        }
#pragma unroll
        for (int i = 0; i < 4; ++i)
#pragma unroll
            for (int j = 0; j < 4; ++j)
                acc[i][j] = __builtin_amdgcn_mfma_f32_16x16x32_bf16(fa[i], fb[j], acc[i][j], 0, 0, 0);
    }
    const int col = lane & 15, rq = (lane >> 4) * 4;
#pragma unroll
    for (int i = 0; i < 4; ++i) {
#pragma unroll
        for (int rg = 0; rg < 4; ++rg) {
            const int d = m0 + (wv >> 1) * 64 + i * 16 + rq + rg;
            const long dbase = (long)((d >> 3) & 31) * 8192 + (long)(d >> 8) * 256 + (long)(d & 7) * 32;
#pragma unroll
            for (int j = 0; j < 4; ++j) {
                const int n = (wv & 1) * 64 + j * 16 + col;
                out0[(long)(b0 + (n >> 5)) * 262144 + dbase + (n & 31)] = acc[i][j][rg];
            }
        }
    }
}

// ---------------------------------------------------------------------------
extern "C" void kernel_launch(void* const* d_in, const int* in_sizes, int n_in,
                              void* d_out, int out_size, void* d_ws, size_t ws_size,
                              hipStream_t stream) {
    const float* inp = (const float*)d_in[0];
    const float* ctx = (const float*)d_in[1];
    const float* Wm  = (const float*)d_in[2];
    float* out0 = (float*)d_out;
    float* out1 = out0 + 16777216;

    float* wsf = (float*)d_ws;
    float* tWpart = wsf;                                   // 8*2048*256 = 4,194,304 f
    unsigned short* usb = (unsigned short*)(wsf + 4194304);
    unsigned short* Wt_hi = usb;                           // 2,097,152
    unsigned short* Wt_lo = Wt_hi + 2097152;
    unsigned short* Wb_hi = Wt_lo + 2097152;
    unsigned short* ctxAq = Wb_hi + 2097152;               // 524,288

    hipLaunchKernelGGL(k0_prep, dim3(128, 4), dim3(256), 0, stream, Wm, Wt_hi, Wt_lo, Wb_hi);
    hipLaunchKernelGGL(k1_mfma, dim3(2, 16, 8), dim3(256), 0, stream, inp, Wt_hi, Wt_lo, tWpart);
    hipLaunchKernelGGL(k2_logits_softmax, dim3(16, 64), dim3(64), 0, stream, tWpart, ctx, out1);
    hipLaunchKernelGGL(k3_ctxA, dim3(64), dim3(256), 0, stream, ctx, out1, out0 ? ctxAq : ctxAq);
    hipLaunchKernelGGL(k4_mfma, dim3(64, 16), dim3(256), 0, stream, Wb_hi, ctxAq, out0);
}